// Round 10
// baseline (140.486 us; speedup 1.0000x reference)
//
#include <hip/hip_runtime.h>

// Path signature, depth 4, C=8, L=256, N=256.
// MEASUREMENT ROUND: identical R9 kernel launched 4x back-to-back to measure
// the kernel's true duration via the dur_us slope (overhead + 4*kernel),
// since harness fill dispatches (~42us) mask it in the top-5 profile.
// Kernel itself unchanged from R9 (segmented + cndmask select trees).

constexpr int N_SAMP = 256;
constexpr int L_LEN = 256;
constexpr int C_DIM = 8;
constexpr int OUT_PER = 8 + 64 + 512 + 4096; // 4680
constexpr int NSEG = 4;
constexpr int SIG_STRIDE = 4688; // 4680 padded

__global__ __launch_bounds__(1024) void sig_kernel(const float* __restrict__ path,
                                                   float* __restrict__ out) {
    __shared__ float dx[(L_LEN - 1) * C_DIM];   // 2040 floats
    __shared__ float sig[NSEG][SIG_STRIDE];     // 4*4688 floats = 75 KB

    const int n = blockIdx.x;
    const int tid = threadIdx.x;

    // ---- stage increments into LDS (1020 float2's) ----
    const float* p = path + (size_t)n * L_LEN * C_DIM;
    if (tid < 1020) {
        float2 a = *(const float2*)(p + tid * 2);
        float2 b = *(const float2*)(p + tid * 2 + C_DIM);
        *(float2*)(&dx[tid * 2]) = make_float2(b.x - a.x, b.y - a.y);
    }
    __syncthreads();

    // ---- phase 1: per-segment recursion ----
    const int seg = tid >> 8;      // 0..3
    const int r = tid & 255;
    const int i = r >> 5;
    const int j = (r >> 2) & 7;

    const int t0 = seg * 64;
    const int tcnt = (seg == 3) ? 63 : 64;   // wave-uniform

    // loop-invariant selection masks
    const bool ib0 = (i & 1), ib1 = (i & 2), ib2 = (i & 4);
    const bool jb0 = (j & 1), jb1 = (j & 2), jb2 = (j & 4);
    const bool kb0 = (r & 1), kb1 = (r & 2);

    float acc[16];
#pragma unroll
    for (int m = 0; m < 16; ++m) acc[m] = 0.f;
    float s3a = 0.f, s3b = 0.f, s2 = 0.f, s1 = 0.f;

    constexpr float THIRD = 1.f / 3.f;

#pragma unroll 4
    for (int t = 0; t < tcnt; ++t) {
        const float* v = &dx[(t0 + t) * C_DIM];
        float vv[8];
#pragma unroll
        for (int c = 0; c < 8; ++c) vv[c] = v[c]; // 2x ds_read_b128 (broadcast)

        // vi = vv[i] via cndmask tree (i loop-invariant)
        float si01 = ib0 ? vv[1] : vv[0];
        float si23 = ib0 ? vv[3] : vv[2];
        float si45 = ib0 ? vv[5] : vv[4];
        float si67 = ib0 ? vv[7] : vv[6];
        float si03 = ib1 ? si23 : si01;
        float si47 = ib1 ? si67 : si45;
        float vi = ib2 ? si47 : si03;

        // vj = vv[j]
        float sj01 = jb0 ? vv[1] : vv[0];
        float sj23 = jb0 ? vv[3] : vv[2];
        float sj45 = jb0 ? vv[5] : vv[4];
        float sj67 = jb0 ? vv[7] : vv[6];
        float sj03 = jb1 ? sj23 : sj01;
        float sj47 = jb1 ? sj67 : sj45;
        float vj = jb2 ? sj47 : sj03;

        // (vk0, vk1) = (vv[k0], vv[k0+1]), pair index = r&3
        float a01 = kb0 ? vv[2] : vv[0];
        float a23 = kb0 ? vv[6] : vv[4];
        float vk0 = kb1 ? a23 : a01;
        float b01 = kb0 ? vv[3] : vv[1];
        float b23 = kb0 ? vv[7] : vv[5];
        float vk1 = kb1 ? b23 : b01;

        // factored Chen coefficients (all use OLD s1,s2,s3)
        float c4 = fmaf(vj * THIRD, fmaf(0.25f, vi, s1), s2);
        float c3 = fmaf(vj * 0.5f, fmaf(THIRD, vi, s1), s2);
        float f0 = fmaf(c4, 0.5f * vk0, s3a);
        float f1 = fmaf(c4, 0.5f * vk1, s3b);

#pragma unroll
        for (int l = 0; l < 8; ++l) {
            acc[l] = fmaf(f0, vv[l], acc[l]);
            acc[8 + l] = fmaf(f1, vv[l], acc[8 + l]);
        }
        s3a = fmaf(c3, vk0, s3a);
        s3b = fmaf(c3, vk1, s3b);
        s2 = fmaf(fmaf(0.5f, vi, s1), vj, s2);
        s1 += vi;
    }

    // ---- store segment signature to LDS ----
    {
        float* sg = sig[seg];
        if ((r & 31) == 0) sg[i] = s1;
        if ((r & 3) == 0) sg[8 + i * 8 + j] = s2;
        *(float2*)(&sg[72 + r * 2]) = make_float2(s3a, s3b);
        float* s4 = sg + 584 + r * 16;
        *(float4*)(s4) = make_float4(acc[0], acc[1], acc[2], acc[3]);
        *(float4*)(s4 + 4) = make_float4(acc[4], acc[5], acc[6], acc[7]);
        *(float4*)(s4 + 8) = make_float4(acc[8], acc[9], acc[10], acc[11]);
        *(float4*)(s4 + 12) = make_float4(acc[12], acc[13], acc[14], acc[15]);
    }
    __syncthreads();

    // ---- phase 2: 3 sequential Chen combines, result accumulates in sig[0] ----
    const int i4 = tid >> 7;
    const int j4 = (tid >> 4) & 7;
    const int k4 = (tid >> 1) & 7;
    const int l0 = (tid & 1) * 4;
    const int ijk4 = tid >> 1;

    for (int b = 1; b < NSEG; ++b) {
        const float* A = sig[0];
        const float* B = sig[b];

        float a3 = A[72 + ijk4];
        float a2 = A[8 + i4 * 8 + j4];
        float a1 = A[i4];
        float c4v[4];
#pragma unroll
        for (int m = 0; m < 4; ++m) {
            int l = l0 + m;
            float t = A[584 + ijk4 * 8 + l] + B[584 + ijk4 * 8 + l];
            t = fmaf(a3, B[l], t);
            t = fmaf(a2, B[8 + k4 * 8 + l], t);
            t = fmaf(a1, B[72 + j4 * 64 + k4 * 8 + l], t);
            c4v[m] = t;
        }
        float n3 = 0.f, n2 = 0.f, n1 = 0.f;
        if (tid < 512) {
            int ii = tid >> 6, jj = (tid >> 3) & 7, kk = tid & 7;
            n3 = A[72 + tid] + B[72 + tid];
            n3 = fmaf(A[8 + ii * 8 + jj], B[kk], n3);
            n3 = fmaf(A[ii], B[8 + jj * 8 + kk], n3);
        }
        if (tid < 64) {
            int ii = tid >> 3, jj = tid & 7;
            n2 = A[8 + tid] + B[8 + tid] + A[ii] * B[jj];
        }
        if (tid < 8) n1 = A[tid] + B[tid];
        __syncthreads();   // all reads of sig[0] complete

        float* W = sig[0];
#pragma unroll
        for (int m = 0; m < 4; ++m) W[584 + ijk4 * 8 + l0 + m] = c4v[m];
        if (tid < 512) W[72 + tid] = n3;
        if (tid < 64) W[8 + tid] = n2;
        if (tid < 8) W[tid] = n1;
        __syncthreads();
    }

    // ---- coalesced write-out ----
    float* o = out + (size_t)n * OUT_PER;
    for (int idx = tid; idx < OUT_PER; idx += 1024) o[idx] = sig[0][idx];
}

extern "C" void kernel_launch(void* const* d_in, const int* in_sizes, int n_in,
                              void* d_out, int out_size, void* d_ws, size_t ws_size,
                              hipStream_t stream) {
    const float* path = (const float*)d_in[0];
    float* out = (float*)d_out;
    // 4x identical launches: dur_us = overhead + 4*T_kernel. Slope vs R9's
    // single-launch 74.2us isolates T_kernel (3x amplification over noise).
    for (int rep = 0; rep < 4; ++rep) {
        sig_kernel<<<N_SAMP, 1024, 0, stream>>>(path, out);
    }
}

// Round 11
// 101.402 us; speedup vs baseline: 1.3854x; 1.3854x over previous
//
#include <hip/hip_runtime.h>

// Path signature, depth 4, C=8, L=256, N=256.
// R10 slope measurement: T_kernel ~= 22us, harness floor ~= 52us.
// Issue-bound model: ~75 insts/iter/wave, only 16 useful FMAs.
// This version: 8 segments x 128-thread groups; each thread owns
// (i = r>>4, j = (r>>1)&7, k0 = 4*(r&1)) -> acc[4][8] = 32 FMAs/iter,
// halving total thread-iterations (1024x32 vs 1024x64) at same overhead
// per iter. 7 sequential Chen combines via X/Y LDS ping-pong (R9-validated
// combine code). LDS = 2040 + 2*4680 floats = 45.6 KB.

constexpr int N_SAMP = 256;
constexpr int L_LEN = 256;
constexpr int C_DIM = 8;
constexpr int OUT_PER = 8 + 64 + 512 + 4096; // 4680
constexpr int NSEG = 8;

__global__ __launch_bounds__(1024) void sig_kernel(const float* __restrict__ path,
                                                   float* __restrict__ out) {
    __shared__ float dx[(L_LEN - 1) * C_DIM]; // 2040 floats
    __shared__ float X[OUT_PER];              // running signature
    __shared__ float Y[OUT_PER];              // incoming segment signature

    const int n = blockIdx.x;
    const int tid = threadIdx.x;

    // ---- stage increments into LDS (1020 float2's) ----
    const float* p = path + (size_t)n * L_LEN * C_DIM;
    if (tid < 1020) {
        float2 a = *(const float2*)(p + tid * 2);
        float2 b = *(const float2*)(p + tid * 2 + C_DIM);
        *(float2*)(&dx[tid * 2]) = make_float2(b.x - a.x, b.y - a.y);
    }
    __syncthreads();

    // ---- phase 1: per-segment recursion, 32 level-4 elems per thread ----
    const int seg = tid >> 7;     // 0..7
    const int r = tid & 127;
    const int i = r >> 4;         // 0..7
    const int j = (r >> 1) & 7;   // 0..7
    const bool khb = (r & 1);     // k0 = 4*(r&1)

    const int t0 = seg * 32;
    const int tcnt = (seg == 7) ? 31 : 32;   // wave-uniform (waves 14,15 both seg 7)

    float acc[4][8];
#pragma unroll
    for (int m = 0; m < 4; ++m)
#pragma unroll
        for (int l = 0; l < 8; ++l) acc[m][l] = 0.f;
    float s3[4] = {0.f, 0.f, 0.f, 0.f};
    float s2 = 0.f, s1 = 0.f;

    constexpr float THIRD = 1.f / 3.f;

#pragma unroll 4
    for (int t = 0; t < tcnt; ++t) {
        const float* v = &dx[(t0 + t) * C_DIM];
        float vv[8];
#pragma unroll
        for (int c = 0; c < 8; ++c) vv[c] = v[c]; // 2x ds_read_b128 broadcast
        float vi = v[i];                          // ds_read_b32 (<=8 distinct words)
        float vj = v[j];                          // ds_read_b32
        float vk[4];
#pragma unroll
        for (int m = 0; m < 4; ++m) vk[m] = khb ? vv[4 + m] : vv[m]; // 4 cndmask

        // factored Chen coefficients (OLD s1,s2,s3)
        float c4 = fmaf(vj * THIRD, fmaf(0.25f, vi, s1), s2);
        float c3 = fmaf(vj * 0.5f, fmaf(THIRD, vi, s1), s2);

#pragma unroll
        for (int m = 0; m < 4; ++m) {
            float f = fmaf(c4, 0.5f * vk[m], s3[m]);
#pragma unroll
            for (int l = 0; l < 8; ++l) acc[m][l] = fmaf(f, vv[l], acc[m][l]);
            s3[m] = fmaf(c3, vk[m], s3[m]);
        }
        s2 = fmaf(fmaf(0.5f, vi, s1), vj, s2);
        s1 += vi;
    }

    // ---- segment-signature store (layout: s1[8] s2[64] s3[512] s4[4096]) ----
    auto write_sig = [&](float* sg) {
        if ((r & 15) == 0) sg[i] = s1;
        if (!khb) sg[8 + i * 8 + j] = s2;
        *(float4*)(&sg[72 + r * 4]) = make_float4(s3[0], s3[1], s3[2], s3[3]);
        float* s4p = sg + 584 + r * 32; // 32*r = i*512 + j*64 + kh*32
#pragma unroll
        for (int m = 0; m < 4; ++m) {
            *(float4*)(s4p + m * 8) = make_float4(acc[m][0], acc[m][1], acc[m][2], acc[m][3]);
            *(float4*)(s4p + m * 8 + 4) = make_float4(acc[m][4], acc[m][5], acc[m][6], acc[m][7]);
        }
    };

    if (seg == 0) write_sig(X);
    __syncthreads();

    // ---- phase 2: 7 sequential Chen combines X = X (x) Y ----
    const int ci = tid >> 7;
    const int cj = (tid >> 4) & 7;
    const int ck = (tid >> 1) & 7;
    const int l0 = (tid & 1) * 4;
    const int ijk4 = tid >> 1;

    for (int b = 1; b < NSEG; ++b) {
        if (seg == b) write_sig(Y);
        __syncthreads();

        // read + compute (no writes to X)
        float a3 = X[72 + ijk4];
        float a2 = X[8 + ci * 8 + cj];
        float a1 = X[ci];
        float c4v[4];
#pragma unroll
        for (int m = 0; m < 4; ++m) {
            int l = l0 + m;
            float t = X[584 + ijk4 * 8 + l] + Y[584 + ijk4 * 8 + l];
            t = fmaf(a3, Y[l], t);
            t = fmaf(a2, Y[8 + ck * 8 + l], t);
            t = fmaf(a1, Y[72 + cj * 64 + ck * 8 + l], t);
            c4v[m] = t;
        }
        float n3 = 0.f, n2 = 0.f, n1 = 0.f;
        if (tid < 512) {
            int ii = tid >> 6, jj = (tid >> 3) & 7, kk = tid & 7;
            n3 = X[72 + tid] + Y[72 + tid];
            n3 = fmaf(X[8 + ii * 8 + jj], Y[kk], n3);
            n3 = fmaf(X[ii], Y[8 + jj * 8 + kk], n3);
        }
        if (tid < 64) {
            int ii = tid >> 3, jj = tid & 7;
            n2 = X[8 + tid] + Y[8 + tid] + X[ii] * Y[jj];
        }
        if (tid < 8) n1 = X[tid] + Y[tid];
        __syncthreads();   // all reads of X,Y complete

        // write phase
#pragma unroll
        for (int m = 0; m < 4; ++m) X[584 + ijk4 * 8 + l0 + m] = c4v[m];
        if (tid < 512) X[72 + tid] = n3;
        if (tid < 64) X[8 + tid] = n2;
        if (tid < 8) X[tid] = n1;
        __syncthreads();
    }

    // ---- coalesced write-out ----
    float* o = out + (size_t)n * OUT_PER;
    for (int idx = tid; idx < OUT_PER; idx += 1024) o[idx] = X[idx];
}

extern "C" void kernel_launch(void* const* d_in, const int* in_sizes, int n_in,
                              void* d_out, int out_size, void* d_ws, size_t ws_size,
                              hipStream_t stream) {
    const float* path = (const float*)d_in[0];
    float* out = (float*)d_out;
    sig_kernel<<<N_SAMP, 1024, 0, stream>>>(path, out);
}

// Round 12
// 69.055 us; speedup vs baseline: 2.0344x; 1.4684x over previous
//
#include <hip/hip_runtime.h>

// Path signature, depth 4, C=8, L=256, N=256.
// R11 post-mortem: VGPR_Count=48 with ~55 live floats => acc spilled to
// scratch (launch_bounds(1024) VGPR cap), explaining 54us. This version:
// 512-thread blocks (8 waves, VGPR cap 256, no spill), NSEG=8, wave=segment,
// lane owns (i=r>>3, j=r&7, all k,l): acc[8][8] -> 64 useful FMA / ~96-inst
// iter, no k-selects. Level-4 LDS rows padded to stride 68 (+4) for
// minimal-conflict b128 access. X4 lives in registers across all 7 combines;
// only X3/X2/X1 round-trip LDS. 2 barriers per combine.

constexpr int N_SAMP = 256;
constexpr int L_LEN = 256;
constexpr int OUT_PER = 4680;     // 8 + 64 + 512 + 4096
constexpr int NSEG = 8;
constexpr int S4 = 584;           // level-4 offset in signature layout
constexpr int ROW = 68;           // padded row stride (64 + 4) for LDS level-4
constexpr int SIG_WORDS = S4 + ROW * 64; // 4936

__global__ __launch_bounds__(512) void sig_kernel(const float* __restrict__ path,
                                                  float* __restrict__ out) {
    __shared__ __align__(16) float dx[(L_LEN - 1) * 8]; // 2040 floats
    __shared__ __align__(16) float X[SIG_WORDS];        // running signature
    __shared__ __align__(16) float Y[SIG_WORDS];        // incoming segment sig

    const int n = blockIdx.x;
    const int tid = threadIdx.x;

    // ---- stage increments ----
    const float* p = path + (size_t)n * L_LEN * 8;
    if (tid < 510) {
        float4 a = *(const float4*)(p + tid * 4);
        float4 b = *(const float4*)(p + tid * 4 + 8);
        *(float4*)(&dx[tid * 4]) = make_float4(b.x - a.x, b.y - a.y, b.z - a.z, b.w - a.w);
    }
    __syncthreads();

    // ---- phase 1: wave w computes segment w's signature ----
    const int seg = tid >> 6;   // == wave id
    const int r = tid & 63;
    const int i = r >> 3;
    const int j = r & 7;
    const int t0 = seg * 32;
    const int tcnt = (seg == 7) ? 31 : 32;  // wave-uniform

    float acc[8][8];
#pragma unroll
    for (int k = 0; k < 8; ++k)
#pragma unroll
        for (int l = 0; l < 8; ++l) acc[k][l] = 0.f;
    float s3[8] = {0.f, 0.f, 0.f, 0.f, 0.f, 0.f, 0.f, 0.f};
    float s2 = 0.f, s1 = 0.f;
    constexpr float THIRD = 1.f / 3.f;

#pragma unroll 2
    for (int t = 0; t < tcnt; ++t) {
        const float* v = &dx[(t0 + t) * 8];
        float4 v0 = *(const float4*)(v);       // broadcast ds_read_b128
        float4 v1 = *(const float4*)(v + 4);
        float vv[8] = {v0.x, v0.y, v0.z, v0.w, v1.x, v1.y, v1.z, v1.w};
        float vi = v[i];   // ds_read_b32, 8 distinct words: conflict-free
        float vj = v[j];

        float c4 = fmaf(vj * THIRD, fmaf(0.25f, vi, s1), s2);
        float c3 = fmaf(vj * 0.5f, fmaf(THIRD, vi, s1), s2);
        float c4h = 0.5f * c4;
#pragma unroll
        for (int k = 0; k < 8; ++k) {
            float f = fmaf(c4h, vv[k], s3[k]);
#pragma unroll
            for (int l = 0; l < 8; ++l) acc[k][l] = fmaf(f, vv[l], acc[k][l]);
            s3[k] = fmaf(c3, vv[k], s3[k]);
        }
        s2 = fmaf(fmaf(0.5f, vi, s1), vj, s2);
        s1 += vi;
    }

    // ---- write a full segment signature to LDS buffer sg ----
    auto write_sig = [&](float* sg) {
        if (j == 0) sg[i] = s1;
        sg[8 + r] = s2;                              // stride-1
        *(float4*)(&sg[72 + 8 * r]) = make_float4(s3[0], s3[1], s3[2], s3[3]);
        *(float4*)(&sg[72 + 8 * r + 4]) = make_float4(s3[4], s3[5], s3[6], s3[7]);
        float* rowp = sg + S4 + ROW * r;             // stride-68: minimal conflict
#pragma unroll
        for (int k = 0; k < 8; ++k) {
            *(float4*)(rowp + 8 * k) = make_float4(acc[k][0], acc[k][1], acc[k][2], acc[k][3]);
            *(float4*)(rowp + 8 * k + 4) = make_float4(acc[k][4], acc[k][5], acc[k][6], acc[k][7]);
        }
    };

    if (seg == 0) write_sig(X);
    __syncthreads();

    // combine-ownership: thread (rr=r, kk=seg) owns level-4 row X4[i=r>>3, j=r&7, k=seg, l=0..7]
    // X4 lives in regs (c4r) across all combines; seed from wave-0's X.
    float c4r[8];
    {
        const float* q = X + S4 + ROW * r + 8 * seg;
        float4 c0 = *(const float4*)(q);
        float4 c1 = *(const float4*)(q + 4);
        c4r[0] = c0.x; c4r[1] = c0.y; c4r[2] = c0.z; c4r[3] = c0.w;
        c4r[4] = c1.x; c4r[5] = c1.y; c4r[6] = c1.z; c4r[7] = c1.w;
    }

    // ---- phase 2: 7 sequential Chen combines X = X (x) Y(seg b) ----
    for (int b = 1; b < NSEG; ++b) {
        if (seg == b) write_sig(Y);
        __syncthreads();

        // --- reads (X old levels + Y), no writes ---
        float4 ya = *(const float4*)(Y);
        float4 yb = *(const float4*)(Y + 4);
        float y1[8] = {ya.x, ya.y, ya.z, ya.w, yb.x, yb.y, yb.z, yb.w};
        const float* y2p = Y + 8 + 8 * seg;           // Y2[kk,l] — wave-broadcast
        float4 u0 = *(const float4*)(y2p);
        float4 u1 = *(const float4*)(y2p + 4);
        float y2k[8] = {u0.x, u0.y, u0.z, u0.w, u1.x, u1.y, u1.z, u1.w};
        const float* y3p = Y + 72 + 64 * j + 8 * seg; // Y3[j,kk,l]
        float4 w0 = *(const float4*)(y3p);
        float4 w1 = *(const float4*)(y3p + 4);
        float y3[8] = {w0.x, w0.y, w0.z, w0.w, w1.x, w1.y, w1.z, w1.w};
        const float* y4p = Y + S4 + ROW * r + 8 * seg; // Y4 own row
        float4 z0 = *(const float4*)(y4p);
        float4 z1 = *(const float4*)(y4p + 4);
        float y4[8] = {z0.x, z0.y, z0.z, z0.w, z1.x, z1.y, z1.z, z1.w};
        float x3o = X[72 + 8 * r + seg];
        float x2o = X[8 + r];
        float x1o = X[i];

        // new level-3 element (index tid): i'=tid>>6, j'=(tid>>3)&7, k'=tid&7
        float n3 = X[72 + tid] + Y[72 + tid];
        n3 = fmaf(X[8 + (tid >> 3)], Y[tid & 7], n3);
        n3 = fmaf(X[tid >> 6], Y[8 + (tid & 63)], n3);
        float n2 = 0.f, n1 = 0.f;
        if (tid < 64) n2 = X[8 + tid] + Y[8 + tid] + X[tid >> 3] * Y[tid & 7];
        if (tid < 8) n1 = X[tid] + Y[tid];

        // --- level-4 update entirely in registers ---
#pragma unroll
        for (int l = 0; l < 8; ++l) {
            float t = c4r[l] + y4[l];
            t = fmaf(x3o, y1[l], t);
            t = fmaf(x2o, y2k[l], t);
            t = fmaf(x1o, y3[l], t);
            c4r[l] = t;
        }

        __syncthreads();   // all reads of X/Y done
        X[72 + tid] = n3;
        if (tid < 64) X[8 + tid] = n2;
        if (tid < 8) X[tid] = n1;
        // next iteration's Y-write + barrier orders these before next reads
    }

    // ---- write-out: dump c4r into Y's tail in OUTPUT layout, then coalesce ----
    {
        float* q = Y + S4 + 64 * r + 8 * seg;  // 584 + 512i + 64j + 8k
        *(float4*)(q) = make_float4(c4r[0], c4r[1], c4r[2], c4r[3]);
        *(float4*)(q + 4) = make_float4(c4r[4], c4r[5], c4r[6], c4r[7]);
    }
    __syncthreads();
    float* o = out + (size_t)n * OUT_PER;
    for (int idx = tid; idx < OUT_PER; idx += 512) {
        o[idx] = (idx < S4) ? X[idx] : Y[idx];
    }
}

extern "C" void kernel_launch(void* const* d_in, const int* in_sizes, int n_in,
                              void* d_out, int out_size, void* d_ws, size_t ws_size,
                              hipStream_t stream) {
    const float* path = (const float*)d_in[0];
    float* out = (float*)d_out;
    sig_kernel<<<N_SAMP, 512, 0, stream>>>(path, out);
}